// Round 2
// baseline (405.292 us; speedup 1.0000x reference)
//
#include <hip/hip_runtime.h>
#include <math.h>

#define BB 64
#define SS 2048
#define DD 512
#define CH 16
#define ROWS (SS/CH)        // 128 rows per chunk
#define WROWS (ROWS/4)      // 32 rows per wave
#define RPI 4               // rows per wave-iteration (batched online softmax)
#define ITERS (WROWS/RPI)   // 8 iterations per wave

// ---------------- kernel 1: w[b,d] = (concat(c1,q)[b,:] . W_d2d[d,:] + b_d[d]) * W_1d[d]
__global__ __launch_bounds__(128) void k_w(
    const float* __restrict__ c1, const float* __restrict__ q,
    const float* __restrict__ Wd, const float* __restrict__ bd,
    const float* __restrict__ W1, float* __restrict__ w)
{
    __shared__ float conc[2*DD];
    const int b = blockIdx.y;
    const int t = threadIdx.x;
    for (int i = t; i < DD; i += 128) {
        conc[i]      = c1[b*DD + i];
        conc[DD + i] = q[b*DD + i];
    }
    __syncthreads();
    const int d = blockIdx.x * 128 + t;
    const float4* Wr = (const float4*)(Wd + (size_t)d * (2*DD));
    const float4* cc = (const float4*)conc;
    float acc = 0.f;
    #pragma unroll 8
    for (int k = 0; k < (2*DD)/4; ++k) {
        float4 a = Wr[k];
        float4 c = cc[k];
        acc += a.x*c.x + a.y*c.y + a.z*c.z + a.w*c.w;
    }
    w[b*DD + d] = (acc + bd[d]) * W1[d];
}

// ---------------- kernel 2: online-softmax partial over a chunk of 128 rows
// 4 waves/block; wave owns 32 contiguous rows; processes 4 rows per iteration.
// Batched reduction: 4 independent shfl butterflies pipeline (no serial chain
// per row); one max/rescale per 4 rows instead of per row; 8 KB/wave in flight.
__global__ __launch_bounds__(256) void k_pass(
    const float* __restrict__ cw, const float* __restrict__ w,
    float* __restrict__ pm, float* __restrict__ pl, float* __restrict__ pacc)
{
    const int blk  = blockIdx.x;
    const int b    = blk >> 4;        // /CH
    const int ch   = blk & (CH - 1);
    const int tid  = threadIdx.x;
    const int wave = tid >> 6;
    const int lane = tid & 63;

    // per-lane slice of w: d = 4*lane .. +3  and  256 + 4*lane .. +3
    const float4* wb = (const float4*)(w + b*DD);
    const float4 w0 = wb[lane];
    const float4 w1 = wb[64 + lane];

    // wave's contiguous 32-row strip
    const float* rb = cw + ((size_t)b*SS + (size_t)ch*ROWS + (size_t)wave*WROWS) * DD;

    // load first group of 4 rows
    float4 c0[RPI], c1v[RPI];
    #pragma unroll
    for (int r = 0; r < RPI; ++r) {
        const float4* p = (const float4*)(rb + (size_t)r * DD);
        c0[r]  = p[lane];
        c1v[r] = p[64 + lane];
    }

    float m = -INFINITY, l = 0.f;
    float4 a0 = make_float4(0,0,0,0), a1 = make_float4(0,0,0,0);

    #pragma unroll 2
    for (int i = 0; i < ITERS; ++i) {
        // prefetch next group (clamped on last iter: re-reads hot lines, cheap)
        const int nx = (i + 1 < ITERS) ? (i + 1) : i;
        const float* nbase = rb + (size_t)nx * RPI * DD;
        float4 n0[RPI], n1[RPI];
        #pragma unroll
        for (int r = 0; r < RPI; ++r) {
            const float4* p = (const float4*)(nbase + (size_t)r * DD);
            n0[r] = p[lane];
            n1[r] = p[64 + lane];
        }

        // 4 per-lane partial dots
        float d_[RPI];
        #pragma unroll
        for (int r = 0; r < RPI; ++r) {
            d_[r] = c0[r].x*w0.x + c0[r].y*w0.y + c0[r].z*w0.z + c0[r].w*w0.w
                  + c1v[r].x*w1.x + c1v[r].y*w1.y + c1v[r].z*w1.z + c1v[r].w*w1.w;
        }
        // 4 independent butterflies — pipelined through the 6 steps
        #pragma unroll
        for (int off = 32; off; off >>= 1) {
            #pragma unroll
            for (int r = 0; r < RPI; ++r) d_[r] += __shfl_xor(d_[r], off, 64);
        }

        // batched online-softmax update (one rescale per 4 rows)
        float mn = fmaxf(fmaxf(d_[0], d_[1]), fmaxf(d_[2], d_[3]));
        mn = fmaxf(mn, m);
        const float alpha = __expf(m - mn);   // first iter: expf(-inf) = 0
        m = mn;
        float pr[RPI];
        #pragma unroll
        for (int r = 0; r < RPI; ++r) pr[r] = __expf(d_[r] - m);
        l = l*alpha + (pr[0] + pr[1] + pr[2] + pr[3]);
        a0.x *= alpha; a0.y *= alpha; a0.z *= alpha; a0.w *= alpha;
        a1.x *= alpha; a1.y *= alpha; a1.z *= alpha; a1.w *= alpha;
        #pragma unroll
        for (int r = 0; r < RPI; ++r) {
            a0.x += pr[r]*c0[r].x;  a0.y += pr[r]*c0[r].y;
            a0.z += pr[r]*c0[r].z;  a0.w += pr[r]*c0[r].w;
            a1.x += pr[r]*c1v[r].x; a1.y += pr[r]*c1v[r].y;
            a1.z += pr[r]*c1v[r].z; a1.w += pr[r]*c1v[r].w;
        }

        // rotate buffers
        #pragma unroll
        for (int r = 0; r < RPI; ++r) { c0[r] = n0[r]; c1v[r] = n1[r]; }
    }

    // combine 4 waves within the block
    __shared__ float lm[4], ll[4];
    __shared__ float lacc[4][DD];
    if (lane == 0) lm[wave] = m;
    __syncthreads();
    const float M = fmaxf(fmaxf(lm[0], lm[1]), fmaxf(lm[2], lm[3]));
    const float beta = __expf(m - M);
    float4* lw = (float4*)lacc[wave];
    lw[lane]      = make_float4(a0.x*beta, a0.y*beta, a0.z*beta, a0.w*beta);
    lw[64 + lane] = make_float4(a1.x*beta, a1.y*beta, a1.z*beta, a1.w*beta);
    if (lane == 0) ll[wave] = l * beta;
    __syncthreads();
    const float s0 = lacc[0][tid]     + lacc[1][tid]     + lacc[2][tid]     + lacc[3][tid];
    const float s1 = lacc[0][tid+256] + lacc[1][tid+256] + lacc[2][tid+256] + lacc[3][tid+256];
    pacc[(size_t)blk*DD + tid]       = s0;
    pacc[(size_t)blk*DD + tid + 256] = s1;
    if (tid == 0) {
        pm[blk] = M;
        pl[blk] = ll[0] + ll[1] + ll[2] + ll[3];
    }
}

// ---------------- kernel 3: merge 16 chunk-partials per batch (float2-vectorized)
__global__ __launch_bounds__(256) void k_comb(
    const float* __restrict__ pm, const float* __restrict__ pl,
    const float* __restrict__ pacc, float* __restrict__ out)
{
    const int b = blockIdx.x;
    const int tid = threadIdx.x;
    float M = -INFINITY;
    #pragma unroll
    for (int p = 0; p < CH; ++p) M = fmaxf(M, pm[b*CH + p]);
    float L = 0.f;
    float sx = 0.f, sy = 0.f;
    #pragma unroll
    for (int p = 0; p < CH; ++p) {
        const float sc = __expf(pm[b*CH + p] - M);
        L += pl[b*CH + p] * sc;
        const float2 v = ((const float2*)(pacc + (size_t)(b*CH + p)*DD))[tid];
        sx += sc * v.x;
        sy += sc * v.y;
    }
    const float inv = 1.f / L;
    ((float2*)(out + b*DD))[tid] = make_float2(sx*inv, sy*inv);
}

extern "C" void kernel_launch(void* const* d_in, const int* in_sizes, int n_in,
                              void* d_out, int out_size, void* d_ws, size_t ws_size,
                              hipStream_t stream)
{
    const float* c1 = (const float*)d_in[0];   // c_i_1 [B,D]
    const float* q  = (const float*)d_in[1];   // q     [B,D]
    const float* cw = (const float*)d_in[2];   // cw_s  [B,S,D]
    const float* Wd = (const float*)d_in[3];   // W_d2d [D,2D]
    const float* bd = (const float*)d_in[4];   // b_d   [D]
    const float* W1 = (const float*)d_in[5];   // W_1d  [1,D]
    // d_in[6] = b_1: constant logit shift -> cancels in softmax, unused.

    float* out  = (float*)d_out;
    float* ws   = (float*)d_ws;
    float* w    = ws;                    // B*D          = 32768 floats
    float* pm   = w  + BB*DD;            // B*CH         = 1024
    float* pl   = pm + BB*CH;            // B*CH         = 1024
    float* pacc = pl + BB*CH;            // B*CH*D       = 524288

    k_w   <<<dim3(DD/128, BB), 128, 0, stream>>>(c1, q, Wd, bd, W1, w);
    k_pass<<<BB*CH,            256, 0, stream>>>(cw, w, pm, pl, pacc);
    k_comb<<<BB,               256, 0, stream>>>(pm, pl, pacc, out);
}